// Round 1
// baseline (8693.264 us; speedup 1.0000x reference)
//
#include <hip/hip_runtime.h>
#include <stdint.h>

// SuperpointGenerator: per-batch voxel id -> count -> top-256 by (count desc, id asc)
// -> labels 0..255 (else -1); if U<=256, label = dense rank by ascending id.

namespace {
constexpr int B_ = 16;
constexpr int N_ = 262144;          // 2^18 points per batch
constexpr int LOGN_ = 18;
constexpr int K_ = 256;
constexpr int LOGC_ = 18;
constexpr int C_ = 1 << LOGC_;      // hash table slots per batch (U <= N = C)
constexpr unsigned CMASK_ = C_ - 1;
constexpr int SENT_ = (int)0x80000000;  // empty-slot marker (never a real id here)
}

__device__ __forceinline__ unsigned hash_id(int id) {
    unsigned h = (unsigned)id * 2654435761u;   // Knuth multiplicative
    return h >> (32 - LOGC_);                  // upper bits -> [0, C)
}

__global__ void k_init(int* __restrict__ ids, unsigned* __restrict__ cnts,
                       unsigned* __restrict__ meta /* [B] U, [B..2B) csize */) {
    size_t i = (size_t)blockIdx.x * blockDim.x + threadIdx.x;
    if (i < (size_t)B_ * C_) { ids[i] = SENT_; cnts[i] = 0u; }
    if (i < 2 * B_) meta[i] = 0u;
}

__global__ void k_build(const float* __restrict__ coords, int* __restrict__ ids,
                        unsigned* __restrict__ cnts, int* __restrict__ pslot,
                        unsigned* __restrict__ meta) {
    int i = blockIdx.x * blockDim.x + threadIdx.x;
    if (i >= B_ * N_) return;
    int b = i >> LOGN_;
    const float* c = coords + (size_t)i * 3;
    // Must match jnp.floor(c / 0.2f) bit-exactly: IEEE fp32 division, no recip.
    int vx = (int)floorf(c[0] / 0.2f);
    int vy = (int)floorf(c[1] / 0.2f);
    int vz = (int)floorf(c[2] / 0.2f);
    int id = vx * 10000 + vy * 100 + vz;

    int* tids = ids + (size_t)b * C_;
    unsigned* tc = cnts + (size_t)b * C_;
    unsigned s = hash_id(id);
    while (true) {
        int prev = atomicCAS(&tids[s], SENT_, id);
        if (prev == SENT_ || prev == id) {
            atomicAdd(&tc[s], 1u);
            if (prev == SENT_) atomicAdd(&meta[b], 1u);  // count uniques U
            break;
        }
        s = (s + 1) & CMASK_;
    }
    pslot[i] = (int)s;
}

__global__ void k_compact(const int* __restrict__ ids, const unsigned* __restrict__ cnts,
                          const unsigned* __restrict__ meta,
                          unsigned long long* __restrict__ ckeys,
                          unsigned* __restrict__ csize) {
    size_t i = (size_t)blockIdx.x * blockDim.x + threadIdx.x;
    if (i >= (size_t)B_ * C_) return;
    int b = (int)(i >> LOGC_);
    int id = ids[i];
    if (id == SENT_) return;
    unsigned u = (unsigned)id ^ 0x80000000u;   // signed asc -> unsigned asc
    unsigned long long key;
    if (meta[b] > (unsigned)K_) {
        // order by (count desc, id asc): larger key = higher priority
        key = ((unsigned long long)cnts[i] << 32) | (unsigned long long)(~u);
    } else {
        // U<=K branch: labels are dense rank by id asc -> key = ~u only
        key = (unsigned long long)(~u);
    }
    unsigned pos = atomicAdd(&csize[b], 1u);
    ckeys[(size_t)b * C_ + pos] = key;
}

__global__ void __launch_bounds__(1024)
k_select(const unsigned* __restrict__ meta, const unsigned long long* __restrict__ ckeys,
         const int* __restrict__ ids, unsigned* __restrict__ cnts /* becomes labels */) {
    int b = blockIdx.x;
    int U = (int)meta[b];
    const unsigned long long* keys = ckeys + (size_t)b * C_;

    __shared__ unsigned hist[256];
    __shared__ unsigned long long skeys[K_];
    __shared__ int s_sel;
    __shared__ unsigned long long s_prefix;
    __shared__ int s_rem;

    int t = threadIdx.x;
    unsigned long long thr = 0ull;

    if (U > K_) {
        // MSB-first radix select: exact 256th-largest key. Keys < 2^50
        // (count<=2^18 in bits 32..49), so bytes 6..0 suffice. Keys unique.
        unsigned long long prefix = 0ull;
        int rem = K_;
        for (int bp = 6; bp >= 0; --bp) {
            if (t < 256) hist[t] = 0u;
            __syncthreads();
            unsigned long long hi = ~0ull << (8 * (bp + 1));
            for (int i = t; i < U; i += blockDim.x) {
                unsigned long long k = keys[i];
                if ((k & hi) == (prefix & hi))
                    atomicAdd(&hist[(unsigned)(k >> (8 * bp)) & 255u], 1u);
            }
            __syncthreads();
            if (t == 0) {
                int cum = 0;
                for (int bin = 255; bin >= 0; --bin) {
                    int cc = (int)hist[bin];
                    if (cum + cc >= rem) {
                        s_prefix = prefix | ((unsigned long long)bin << (8 * bp));
                        s_rem = rem - cum;
                        break;
                    }
                    cum += cc;
                }
            }
            __syncthreads();
            prefix = s_prefix;
            rem = s_rem;
        }
        thr = prefix;  // exactly 256 keys are >= thr (keys unique)
    }

    if (t == 0) s_sel = 0;
    __syncthreads();
    if (U > K_) {
        for (int i = t; i < U; i += blockDim.x) {
            unsigned long long k = keys[i];
            if (k >= thr) { int p = atomicAdd(&s_sel, 1); skeys[p] = k; }
        }
    } else {
        for (int i = t; i < U; i += blockDim.x) {
            int p = atomicAdd(&s_sel, 1); skeys[p] = keys[i];
        }
    }
    __syncthreads();
    int S = s_sel;  // ==256 when U>K, else ==U

    // Reuse cnts as the per-slot label table: default -1.
    unsigned* lab = cnts + (size_t)b * C_;
    for (int i = t; i < C_; i += blockDim.x) lab[i] = 0xFFFFFFFFu;
    __syncthreads();

    // Rank-sort the <=256 survivors descending; rank = final label.
    if (t < S) {
        unsigned long long k = skeys[t];
        int rank = 0;
        for (int j = 0; j < S; ++j) rank += (skeys[j] > k);
        unsigned u = ~((unsigned)k);
        int id = (int)(u ^ 0x80000000u);
        const int* tids = ids + (size_t)b * C_;
        unsigned s = hash_id(id);
        while (tids[s] != id) s = (s + 1) & CMASK_;
        lab[s] = (unsigned)rank;
    }
}

__global__ void k_label(const int* __restrict__ pslot, const unsigned* __restrict__ lab,
                        int* __restrict__ out) {
    int i = blockIdx.x * blockDim.x + threadIdx.x;
    if (i >= B_ * N_) return;
    int b = i >> LOGN_;
    out[i] = (int)lab[(size_t)b * C_ + pslot[i]];
}

extern "C" void kernel_launch(void* const* d_in, const int* in_sizes, int n_in,
                              void* d_out, int out_size, void* d_ws, size_t ws_size,
                              hipStream_t stream) {
    const float* coords = (const float*)d_in[0];
    int* out = (int*)d_out;

    // Workspace layout (80 MB + meta):
    char* w = (char*)d_ws;
    size_t off = 0;
    int* ids = (int*)(w + off);                 off += (size_t)B_ * C_ * 4;   // 16 MB
    unsigned* cnts = (unsigned*)(w + off);      off += (size_t)B_ * C_ * 4;   // 16 MB
    int* pslot = (int*)(w + off);               off += (size_t)B_ * N_ * 4;   // 16 MB
    unsigned long long* ckeys =
        (unsigned long long*)(w + off);         off += (size_t)B_ * C_ * 8;   // 32 MB
    unsigned* meta = (unsigned*)(w + off);      // [0..B): U, [B..2B): csize
    unsigned* csize = meta + B_;

    int threads = 256;
    int blocksBC = (B_ * C_ + threads - 1) / threads;
    int blocksBN = (B_ * N_ + threads - 1) / threads;

    k_init<<<blocksBC, threads, 0, stream>>>(ids, cnts, meta);
    k_build<<<blocksBN, threads, 0, stream>>>(coords, ids, cnts, pslot, meta);
    k_compact<<<blocksBC, threads, 0, stream>>>(ids, cnts, meta, ckeys, csize);
    k_select<<<B_, 1024, 0, stream>>>(meta, ckeys, ids, cnts);
    k_label<<<blocksBN, threads, 0, stream>>>(pslot, cnts, out);
}

// Round 2
// 1228.176 us; speedup vs baseline: 7.0782x; 7.0782x over previous
//
#include <hip/hip_runtime.h>
#include <stdint.h>

// SuperpointGenerator: per-batch voxel id -> count -> top-256 by (count desc, id asc)
// -> labels 0..255 (else -1); if U<=256, label = dense rank by ascending id.

namespace {
constexpr int B_ = 16;
constexpr int N_ = 262144;          // 2^18 points per batch
constexpr int LOGN_ = 18;
constexpr int K_ = 256;
constexpr int LOGC_ = 18;
constexpr int C_ = 1 << LOGC_;      // hash table slots per batch (U <= N = C)
constexpr unsigned CMASK_ = C_ - 1;
constexpr int SENT_ = (int)0x80000000;  // empty-slot marker (never a real id here)
}

__device__ __forceinline__ unsigned hash_id(int id) {
    unsigned h = (unsigned)id * 2654435761u;   // Knuth multiplicative
    return h >> (32 - LOGC_);                  // upper bits -> [0, C)
}

__global__ void k_init(int4* __restrict__ ids4, uint4* __restrict__ cnts4,
                       unsigned* __restrict__ csize) {
    int i = blockIdx.x * blockDim.x + threadIdx.x;   // grid == B_*C_/4 exactly
    ids4[i] = make_int4(SENT_, SENT_, SENT_, SENT_);
    cnts4[i] = make_uint4(0u, 0u, 0u, 0u);
    if (i < B_) csize[i] = 0u;
}

__global__ void k_build(const float* __restrict__ coords, int* __restrict__ ids,
                        unsigned* __restrict__ cnts, int* __restrict__ pslot) {
    int i = blockIdx.x * blockDim.x + threadIdx.x;   // grid == B_*N_ exactly
    int b = i >> LOGN_;
    const float* c = coords + (size_t)i * 3;
    // Must match jnp.floor(c / 0.2f) bit-exactly: IEEE fp32 division, no recip.
    int vx = (int)floorf(c[0] / 0.2f);
    int vy = (int)floorf(c[1] / 0.2f);
    int vz = (int)floorf(c[2] / 0.2f);
    int id = vx * 10000 + vy * 100 + vz;

    int* tids = ids + (size_t)b * C_;
    unsigned* tc = cnts + (size_t)b * C_;
    unsigned s = hash_id(id);
    while (true) {
        int prev = atomicCAS(&tids[s], SENT_, id);
        if (prev == SENT_ || prev == id) {
            atomicAdd(&tc[s], 1u);
            break;
        }
        s = (s + 1) & CMASK_;
    }
    pslot[i] = (int)s;
}

// Compact occupied slots into per-batch key arrays (wave-aggregated append),
// and reset cnts[] to 0xFFFFFFFF so it can serve as the label table (-1 default).
__global__ void k_compact(const int* __restrict__ ids, unsigned* __restrict__ cnts,
                          unsigned long long* __restrict__ ckeys,
                          unsigned* __restrict__ csize) {
    int i = blockIdx.x * blockDim.x + threadIdx.x;   // grid == B_*C_ exactly
    int b = i >> LOGC_;                              // wave-uniform (C_ % 256 == 0)
    int id = ids[i];
    bool valid = (id != SENT_);
    unsigned long long key = 0ull;
    if (valid) {
        unsigned u = (unsigned)id ^ 0x80000000u;     // signed asc -> unsigned asc
        // priority key: (count desc, id asc) -> larger key = higher priority
        key = ((unsigned long long)cnts[i] << 32) | (unsigned long long)(~u);
    }
    cnts[i] = 0xFFFFFFFFu;                           // label-table default: -1

    unsigned long long mask = __ballot(valid);
    if (mask != 0ull) {
        int lane = threadIdx.x & 63;
        int leader = __ffsll((unsigned long long)mask) - 1;
        unsigned base = 0u;
        if (lane == leader)
            base = atomicAdd(&csize[b], (unsigned)__popcll(mask));
        base = __shfl(base, leader);                 // leader is active here
        if (valid) {
            unsigned pos = base + (unsigned)__popcll(mask & ((1ull << lane) - 1ull));
            ckeys[(size_t)b * C_ + pos] = key;
        }
    }
}

__global__ void __launch_bounds__(1024)
k_select(const unsigned* __restrict__ csize, const unsigned long long* __restrict__ ckeys,
         const int* __restrict__ ids, unsigned* __restrict__ lab_all) {
    int b = blockIdx.x;
    int U = (int)csize[b];
    const unsigned long long* keys = ckeys + (size_t)b * C_;

    __shared__ unsigned hist[256];
    __shared__ unsigned long long skeys[K_];
    __shared__ int s_sel;
    __shared__ unsigned long long s_prefix;
    __shared__ int s_rem;

    int t = threadIdx.x;
    unsigned long long thr = 0ull;

    if (U > K_) {
        // MSB-first radix select: exact 256th-largest key. Keys < 2^50
        // (count<=2^18 occupies bits 32..49), so bytes 6..0 suffice. Keys unique.
        unsigned long long prefix = 0ull;
        int rem = K_;
        for (int bp = 6; bp >= 0; --bp) {
            if (t < 256) hist[t] = 0u;
            __syncthreads();
            unsigned long long hi = ~0ull << (8 * (bp + 1));
            for (int i = t; i < U; i += blockDim.x) {
                unsigned long long k = keys[i];
                if ((k & hi) == (prefix & hi))
                    atomicAdd(&hist[(unsigned)(k >> (8 * bp)) & 255u], 1u);
            }
            __syncthreads();
            if (t == 0) {
                int cum = 0;
                for (int bin = 255; bin >= 0; --bin) {
                    int cc = (int)hist[bin];
                    if (cum + cc >= rem) {
                        s_prefix = prefix | ((unsigned long long)bin << (8 * bp));
                        s_rem = rem - cum;
                        break;
                    }
                    cum += cc;
                }
            }
            __syncthreads();
            prefix = s_prefix;
            rem = s_rem;
        }
        thr = prefix;  // exactly 256 keys are >= thr (keys unique)
    }

    if (t == 0) s_sel = 0;
    __syncthreads();
    for (int i = t; i < U; i += blockDim.x) {
        unsigned long long k = keys[i];
        if (U <= K_ || k >= thr) { int p = atomicAdd(&s_sel, 1); skeys[p] = k; }
    }
    __syncthreads();
    int S = s_sel;  // ==256 when U>K, else ==U

    // Rank-sort the <=256 survivors; rank = final label.
    // U>K: rank by full key desc (count desc, id asc).
    // U<=K: labels are dense rank by id asc == low-32 (~u) desc.
    if (t < S) {
        unsigned long long k = skeys[t];
        int rank = 0;
        if (U > K_) {
            for (int j = 0; j < S; ++j) rank += (skeys[j] > k);
        } else {
            unsigned kl = (unsigned)k;
            for (int j = 0; j < S; ++j) rank += ((unsigned)skeys[j] > kl);
        }
        unsigned u = ~((unsigned)k);
        int id = (int)(u ^ 0x80000000u);
        const int* tids = ids + (size_t)b * C_;
        unsigned s = hash_id(id);
        while (tids[s] != id) s = (s + 1) & CMASK_;
        lab_all[(size_t)b * C_ + s] = (unsigned)rank;
    }
}

__global__ void k_label(const int* __restrict__ pslot, const unsigned* __restrict__ lab,
                        int* __restrict__ out) {
    int i = blockIdx.x * blockDim.x + threadIdx.x;   // grid == B_*N_ exactly
    int b = i >> LOGN_;
    out[i] = (int)lab[(size_t)b * C_ + pslot[i]];
}

extern "C" void kernel_launch(void* const* d_in, const int* in_sizes, int n_in,
                              void* d_out, int out_size, void* d_ws, size_t ws_size,
                              hipStream_t stream) {
    const float* coords = (const float*)d_in[0];
    int* out = (int*)d_out;

    // Workspace layout (80 MB + meta):
    char* w = (char*)d_ws;
    size_t off = 0;
    int* ids = (int*)(w + off);                 off += (size_t)B_ * C_ * 4;   // 16 MB
    unsigned* cnts = (unsigned*)(w + off);      off += (size_t)B_ * C_ * 4;   // 16 MB
    int* pslot = (int*)(w + off);               off += (size_t)B_ * N_ * 4;   // 16 MB
    unsigned long long* ckeys =
        (unsigned long long*)(w + off);         off += (size_t)B_ * C_ * 8;   // 32 MB
    unsigned* csize = (unsigned*)(w + off);     // [B_]

    int threads = 256;
    int blocksBC = (B_ * C_ + threads - 1) / threads;
    int blocksBN = (B_ * N_ + threads - 1) / threads;
    int blocksI  = (B_ * C_ / 4 + threads - 1) / threads;

    k_init<<<blocksI, threads, 0, stream>>>((int4*)ids, (uint4*)cnts, csize);
    k_build<<<blocksBN, threads, 0, stream>>>(coords, ids, cnts, pslot);
    k_compact<<<blocksBC, threads, 0, stream>>>(ids, cnts, ckeys, csize);
    k_select<<<B_, 1024, 0, stream>>>(csize, ckeys, ids, cnts);
    k_label<<<blocksBN, threads, 0, stream>>>(pslot, cnts, out);
}

// Round 3
// 844.048 us; speedup vs baseline: 10.2995x; 1.4551x over previous
//
#include <hip/hip_runtime.h>
#include <stdint.h>

// SuperpointGenerator: per-batch voxel id -> count -> top-256 by (count desc, id asc)
// -> labels 0..255 (else -1); if U<=256, label = dense rank by ascending id.

namespace {
constexpr int B_ = 16;
constexpr int N_ = 262144;          // 2^18 points per batch
constexpr int LOGN_ = 18;
constexpr int K_ = 256;
constexpr int LOGC_ = 18;
constexpr int C_ = 1 << LOGC_;      // hash table slots per batch (U <= N = C)
constexpr unsigned CMASK_ = C_ - 1;
constexpr int SENT_ = (int)0x80000000;  // empty-slot marker (never a real id here)
}

__device__ __forceinline__ unsigned hash_id(int id) {
    unsigned h = (unsigned)id * 2654435761u;   // Knuth multiplicative
    return h >> (32 - LOGC_);                  // upper bits -> [0, C)
}

__global__ void k_init(int4* __restrict__ ids4, uint4* __restrict__ cnts4,
                       unsigned* __restrict__ csize) {
    int i = blockIdx.x * blockDim.x + threadIdx.x;   // grid == B_*C_/4 exactly
    ids4[i] = make_int4(SENT_, SENT_, SENT_, SENT_);
    cnts4[i] = make_uint4(0u, 0u, 0u, 0u);
    if (i < B_) csize[i] = 0u;
}

__global__ void k_build(const float* __restrict__ coords, int* __restrict__ ids,
                        unsigned* __restrict__ cnts, int* __restrict__ pslot) {
    int i = blockIdx.x * blockDim.x + threadIdx.x;   // grid == B_*N_ exactly
    int b = i >> LOGN_;
    const float* c = coords + (size_t)i * 3;
    // Must match jnp.floor(c / 0.2f) bit-exactly: IEEE fp32 division, no recip.
    int vx = (int)floorf(c[0] / 0.2f);
    int vy = (int)floorf(c[1] / 0.2f);
    int vz = (int)floorf(c[2] / 0.2f);
    int id = vx * 10000 + vy * 100 + vz;

    int* tids = ids + (size_t)b * C_;
    unsigned* tc = cnts + (size_t)b * C_;
    unsigned s = hash_id(id);
    while (true) {
        int prev = atomicCAS(&tids[s], SENT_, id);
        if (prev == SENT_ || prev == id) {
            atomicAdd(&tc[s], 1u);
            break;
        }
        s = (s + 1) & CMASK_;
    }
    pslot[i] = (int)s;
}

// Compact occupied slots into per-batch key arrays (block-aggregated append:
// ONE global atomic per 1024-thread block), and reset cnts[] to 0xFFFFFFFF so
// it can serve as the label table (-1 default).
__global__ void __launch_bounds__(1024)
k_compact(const int* __restrict__ ids, unsigned* __restrict__ cnts,
          unsigned long long* __restrict__ ckeys,
          unsigned* __restrict__ csize) {
    int i = blockIdx.x * 1024 + threadIdx.x;         // grid == B_*C_/1024 exactly
    int b = i >> LOGC_;                              // block-uniform (C_/1024 == 256)
    int id = ids[i];
    bool valid = (id != SENT_);
    unsigned long long key = 0ull;
    if (valid) {
        unsigned u = (unsigned)id ^ 0x80000000u;     // signed asc -> unsigned asc
        // priority key: (count desc, id asc) -> larger key = higher priority
        key = ((unsigned long long)cnts[i] << 32) | (unsigned long long)(~u);
    }
    cnts[i] = 0xFFFFFFFFu;                           // label-table default: -1

    unsigned long long mask = __ballot(valid);
    int lane = threadIdx.x & 63;
    int wave = threadIdx.x >> 6;                     // 0..15

    __shared__ unsigned woff[16];
    __shared__ unsigned blockbase;
    if (lane == 0) woff[wave] = (unsigned)__popcll(mask);
    __syncthreads();
    if (threadIdx.x == 0) {
        unsigned tot = 0;
        for (int w2 = 0; w2 < 16; ++w2) { unsigned c = woff[w2]; woff[w2] = tot; tot += c; }
        blockbase = (tot != 0u) ? atomicAdd(&csize[b], tot) : 0u;
    }
    __syncthreads();
    if (valid) {
        unsigned pos = blockbase + woff[wave]
                     + (unsigned)__popcll(mask & ((1ull << lane) - 1ull));
        ckeys[(size_t)b * C_ + pos] = key;
    }
}

__global__ void __launch_bounds__(1024)
k_select(const unsigned* __restrict__ csize, const unsigned long long* __restrict__ ckeys,
         const int* __restrict__ ids, unsigned* __restrict__ lab_all) {
    int b = blockIdx.x;
    int U = (int)csize[b];
    const unsigned long long* keys = ckeys + (size_t)b * C_;

    __shared__ unsigned hist[1024];
    __shared__ unsigned long long skeys[K_];
    __shared__ int s_sel;
    __shared__ unsigned long long s_prefix;
    __shared__ int s_rem;

    int t = threadIdx.x;
    unsigned long long thr = 0ull;

    if (U > K_) {
        // MSB-first radix select with 10-bit digits: exact 256th-largest key.
        // Keys < 2^50 (count<=2^18 occupies bits 32..49), so 5 passes. Keys unique.
        unsigned long long prefix = 0ull;
        int rem = K_;
        for (int sh = 40; sh >= 0; sh -= 10) {
            hist[t] = 0u;
            __syncthreads();
            unsigned long long hi = ~0ull << (sh + 10);  // bits above current digit
            for (int i = t; i < U; i += 1024) {
                unsigned long long k = keys[i];
                if ((k & hi) == prefix)
                    atomicAdd(&hist[(unsigned)(k >> sh) & 1023u], 1u);
            }
            __syncthreads();
            if (t == 0) {
                int cum = 0;
                for (int bin = 1023; bin >= 0; --bin) {
                    int cc = (int)hist[bin];
                    if (cum + cc >= rem) {
                        s_prefix = prefix | ((unsigned long long)bin << sh);
                        s_rem = rem - cum;
                        break;
                    }
                    cum += cc;
                }
            }
            __syncthreads();
            prefix = s_prefix;
            rem = s_rem;
        }
        thr = prefix;  // exactly 256 keys are >= thr (keys unique)
    }

    if (t == 0) s_sel = 0;
    __syncthreads();
    for (int i = t; i < U; i += 1024) {
        unsigned long long k = keys[i];
        if (U <= K_ || k >= thr) { int p = atomicAdd(&s_sel, 1); skeys[p] = k; }
    }
    __syncthreads();
    int S = s_sel;  // ==256 when U>K, else ==U

    // Rank-sort the <=256 survivors; rank = final label.
    // U>K: rank by full key desc (count desc, id asc).
    // U<=K: labels are dense rank by id asc == low-32 (~u) desc.
    if (t < S) {
        unsigned long long k = skeys[t];
        int rank = 0;
        if (U > K_) {
            for (int j = 0; j < S; ++j) rank += (skeys[j] > k);
        } else {
            unsigned kl = (unsigned)k;
            for (int j = 0; j < S; ++j) rank += ((unsigned)skeys[j] > kl);
        }
        unsigned u = ~((unsigned)k);
        int id = (int)(u ^ 0x80000000u);
        const int* tids = ids + (size_t)b * C_;
        unsigned s = hash_id(id);
        while (tids[s] != id) s = (s + 1) & CMASK_;
        lab_all[(size_t)b * C_ + s] = (unsigned)rank;
    }
}

__global__ void k_label(const int* __restrict__ pslot, const unsigned* __restrict__ lab,
                        int* __restrict__ out) {
    int i = blockIdx.x * blockDim.x + threadIdx.x;   // grid == B_*N_ exactly
    int b = i >> LOGN_;
    out[i] = (int)lab[(size_t)b * C_ + pslot[i]];
}

extern "C" void kernel_launch(void* const* d_in, const int* in_sizes, int n_in,
                              void* d_out, int out_size, void* d_ws, size_t ws_size,
                              hipStream_t stream) {
    const float* coords = (const float*)d_in[0];
    int* out = (int*)d_out;

    // Workspace layout (80 MB + meta):
    char* w = (char*)d_ws;
    size_t off = 0;
    int* ids = (int*)(w + off);                 off += (size_t)B_ * C_ * 4;   // 16 MB
    unsigned* cnts = (unsigned*)(w + off);      off += (size_t)B_ * C_ * 4;   // 16 MB
    int* pslot = (int*)(w + off);               off += (size_t)B_ * N_ * 4;   // 16 MB
    unsigned long long* ckeys =
        (unsigned long long*)(w + off);         off += (size_t)B_ * C_ * 8;   // 32 MB
    unsigned* csize = (unsigned*)(w + off);     // [B_]

    int threads = 256;
    int blocksBN = (B_ * N_ + threads - 1) / threads;
    int blocksI  = (B_ * C_ / 4 + threads - 1) / threads;

    k_init<<<blocksI, threads, 0, stream>>>((int4*)ids, (uint4*)cnts, csize);
    k_build<<<blocksBN, threads, 0, stream>>>(coords, ids, cnts, pslot);
    k_compact<<<B_ * C_ / 1024, 1024, 0, stream>>>(ids, cnts, ckeys, csize);
    k_select<<<B_, 1024, 0, stream>>>(csize, ckeys, ids, cnts);
    k_label<<<blocksBN, threads, 0, stream>>>(pslot, cnts, out);
}

// Round 4
// 798.851 us; speedup vs baseline: 10.8822x; 1.0566x over previous
//
#include <hip/hip_runtime.h>
#include <stdint.h>

// SuperpointGenerator: per-batch voxel id -> count -> top-256 by (count desc, id asc)
// -> labels 0..255 (else -1); if U<=256, label = dense rank by ascending id.
//
// Hash table entry (64-bit): (u << 32) | low32, where u = id ^ 0x80000000 (never 0).
//   During build:  low32 = count (<= 2^18 = 0x40000).
//   After select:  winners' low32 = ~rank (>= 0xFFFFFF00). Decode: low >= 0xFFF00000.

namespace {
constexpr int B_ = 16;
constexpr int N_ = 262144;          // 2^18 points per batch
constexpr int LOGN_ = 18;
constexpr int K_ = 256;
constexpr int LOGC_ = 18;
constexpr int C_ = 1 << LOGC_;      // hash table slots per batch (U <= N = C)
constexpr unsigned CMASK_ = C_ - 1;
typedef unsigned long long ull;
}

__device__ __forceinline__ unsigned hash_id(int id) {
    unsigned h = (unsigned)id * 2654435761u;   // Knuth multiplicative
    return h >> (32 - LOGC_);                  // upper bits -> [0, C)
}

__global__ void k_build(const float* __restrict__ coords, ull* __restrict__ tab,
                        int* __restrict__ pslot) {
    int i = blockIdx.x * blockDim.x + threadIdx.x;   // grid == B_*N_ exactly
    int b = i >> LOGN_;
    const float* c = coords + (size_t)i * 3;
    // Must match jnp.floor(c / 0.2f) bit-exactly: IEEE fp32 division, no recip.
    int vx = (int)floorf(c[0] / 0.2f);
    int vy = (int)floorf(c[1] / 0.2f);
    int vz = (int)floorf(c[2] / 0.2f);
    int id = vx * 10000 + vy * 100 + vz;
    unsigned u = (unsigned)id ^ 0x80000000u;

    ull* t = tab + (size_t)b * C_;
    unsigned s = hash_id(id);
    while (true) {
        ull cur = t[s];              // plain load: stale-safe (slot id is monotone 0->u)
        if (cur == 0ull) {
            ull prev = atomicCAS(&t[s], 0ull, ((ull)u << 32) | 1ull);
            if (prev == 0ull) break;               // inserted
            cur = prev;
        }
        if ((unsigned)(cur >> 32) == u) {          // same voxel: one atomic increment
            atomicAdd(&t[s], 1ull);
            break;
        }
        s = (s + 1) & CMASK_;                      // collision: linear probe
    }
    pslot[i] = (int)s;
}

// Compact occupied slots into per-batch key arrays (block-aggregated append:
// ONE global atomic per 1024-thread block).
__global__ void __launch_bounds__(1024)
k_compact(const ull* __restrict__ tab, ull* __restrict__ ckeys,
          unsigned* __restrict__ csize) {
    int i = blockIdx.x * 1024 + threadIdx.x;         // grid == B_*C_/1024 exactly
    int b = i >> LOGC_;                              // block-uniform (C_/1024 == 256)
    ull e = tab[i];
    bool valid = (e != 0ull);
    // priority key: (count desc, id asc) -> larger key = higher priority
    ull key = ((ull)(unsigned)e << 32) | (ull)(~(unsigned)(e >> 32));

    unsigned long long mask = __ballot(valid);
    int lane = threadIdx.x & 63;
    int wave = threadIdx.x >> 6;                     // 0..15

    __shared__ unsigned woff[16];
    __shared__ unsigned blockbase;
    if (lane == 0) woff[wave] = (unsigned)__popcll(mask);
    __syncthreads();
    if (threadIdx.x == 0) {
        unsigned tot = 0;
        for (int w2 = 0; w2 < 16; ++w2) { unsigned c = woff[w2]; woff[w2] = tot; tot += c; }
        blockbase = (tot != 0u) ? atomicAdd(&csize[b], tot) : 0u;
    }
    __syncthreads();
    if (valid) {
        unsigned pos = blockbase + woff[wave]
                     + (unsigned)__popcll(mask & ((1ull << lane) - 1ull));
        ckeys[(size_t)b * C_ + pos] = key;
    }
}

__global__ void __launch_bounds__(1024)
k_select(const unsigned* __restrict__ csize, const ull* __restrict__ ckeys,
         ull* __restrict__ tab) {
    int b = blockIdx.x;
    int U = (int)csize[b];
    const ull* keys = ckeys + (size_t)b * C_;

    __shared__ unsigned hist[1024];
    __shared__ ull skeys[K_];
    __shared__ int s_sel;
    __shared__ ull s_prefix;
    __shared__ int s_rem;

    int t = threadIdx.x;
    ull thr = 0ull;

    if (U > K_) {
        // MSB-first radix select with 10-bit digits: exact 256th-largest key.
        // Keys < 2^50 (count<=2^18 occupies bits 32..49), so 5 passes. Keys unique.
        ull prefix = 0ull;
        int rem = K_;
        for (int sh = 40; sh >= 0; sh -= 10) {
            hist[t] = 0u;
            __syncthreads();
            ull hi = ~0ull << (sh + 10);             // bits above current digit
            for (int i = t; i < U; i += 1024) {
                ull k = keys[i];
                if ((k & hi) == prefix)
                    atomicAdd(&hist[(unsigned)(k >> sh) & 1023u], 1u);
            }
            __syncthreads();
            if (t == 0) {
                int cum = 0;
                for (int bin = 1023; bin >= 0; --bin) {
                    int cc = (int)hist[bin];
                    if (cum + cc >= rem) {
                        s_prefix = prefix | ((ull)bin << sh);
                        s_rem = rem - cum;
                        break;
                    }
                    cum += cc;
                }
            }
            __syncthreads();
            prefix = s_prefix;
            rem = s_rem;
        }
        thr = prefix;  // exactly 256 keys are >= thr (keys unique)
    }

    if (t == 0) s_sel = 0;
    __syncthreads();
    for (int i = t; i < U; i += 1024) {
        ull k = keys[i];
        if (U <= K_ || k >= thr) { int p = atomicAdd(&s_sel, 1); skeys[p] = k; }
    }
    __syncthreads();
    int S = s_sel;  // ==256 when U>K, else ==U

    // Rank-sort the <=256 survivors; rank = final label.
    // U>K: rank by full key desc (count desc, id asc).
    // U<=K: labels are dense rank by id asc == low-32 (~u) desc.
    if (t < S) {
        ull k = skeys[t];
        int rank = 0;
        if (U > K_) {
            for (int j = 0; j < S; ++j) rank += (skeys[j] > k);
        } else {
            unsigned kl = (unsigned)k;
            for (int j = 0; j < S; ++j) rank += ((unsigned)skeys[j] > kl);
        }
        unsigned u = ~((unsigned)k);
        int id = (int)(u ^ 0x80000000u);
        ull* tb = tab + (size_t)b * C_;
        unsigned s = hash_id(id);
        while ((unsigned)(tb[s] >> 32) != u) s = (s + 1) & CMASK_;
        // Winner: rewrite entry low32 = ~rank (>= 0xFFFFFF00). High bits (u) kept,
        // so concurrent probes in this block still match correctly.
        tb[s] = ((ull)u << 32) | (ull)(~(unsigned)rank);
    }
}

__global__ void k_label(const int* __restrict__ pslot, const ull* __restrict__ tab,
                        int* __restrict__ out) {
    int i = blockIdx.x * blockDim.x + threadIdx.x;   // grid == B_*N_ exactly
    int b = i >> LOGN_;
    ull e = tab[(size_t)b * C_ + pslot[i]];
    unsigned low = (unsigned)e;
    out[i] = (low >= 0xFFF00000u) ? (int)(~low) : -1;
}

extern "C" void kernel_launch(void* const* d_in, const int* in_sizes, int n_in,
                              void* d_out, int out_size, void* d_ws, size_t ws_size,
                              hipStream_t stream) {
    const float* coords = (const float*)d_in[0];
    int* out = (int*)d_out;

    // Workspace layout (80 MB + meta):
    char* w = (char*)d_ws;
    size_t off = 0;
    ull* tab = (ull*)(w + off);                 off += (size_t)B_ * C_ * 8;   // 32 MB
    int* pslot = (int*)(w + off);               off += (size_t)B_ * N_ * 4;   // 16 MB
    ull* ckeys = (ull*)(w + off);               off += (size_t)B_ * C_ * 8;   // 32 MB
    unsigned* csize = (unsigned*)(w + off);     // [B_]

    int threads = 256;
    int blocksBN = (B_ * N_ + threads - 1) / threads;

    hipMemsetAsync(tab, 0, (size_t)B_ * C_ * 8, stream);
    hipMemsetAsync(csize, 0, B_ * sizeof(unsigned), stream);
    k_build<<<blocksBN, threads, 0, stream>>>(coords, tab, pslot);
    k_compact<<<B_ * C_ / 1024, 1024, 0, stream>>>(tab, ckeys, csize);
    k_select<<<B_, 1024, 0, stream>>>(csize, ckeys, tab);
    k_label<<<blocksBN, threads, 0, stream>>>(pslot, tab, out);
}

// Round 5
// 698.667 us; speedup vs baseline: 12.4426x; 1.1434x over previous
//
#include <hip/hip_runtime.h>
#include <stdint.h>

// SuperpointGenerator: per-batch voxel id -> count -> top-256 by (count desc, id asc)
// -> labels 0..255 (else -1); if U<=256, label = dense rank by ascending id.
//
// Hash table entry (64-bit): (u << 32) | low32, where u = id ^ 0x80000000 (never 0).
//   During build:  low32 = count (<= 2^18 = 0x40000).
//   After select:  winners' low32 = ~rank (>= 0xFFFFFF00). Decode: low >= 0xFFF00000.
//
// XCD-locality: blocks are remapped so every block touching batch b's table has
// blockIdx % 8 == b % 8. With MI300-series round-robin block->XCD dispatch, batch
// b's 2 MB table region is only touched by XCD b%8 (2 batches = 4 MB = one L2),
// so table atomics stay XCD-local instead of ping-ponging across 8 L2s.

namespace {
constexpr int B_ = 16;
constexpr int N_ = 262144;          // 2^18 points per batch
constexpr int LOGN_ = 18;
constexpr int K_ = 256;
constexpr int LOGC_ = 18;
constexpr int C_ = 1 << LOGC_;      // hash table slots per batch (U <= N = C)
constexpr unsigned CMASK_ = C_ - 1;
typedef unsigned long long ull;
}

__device__ __forceinline__ unsigned hash_id(int id) {
    unsigned h = (unsigned)id * 2654435761u;   // Knuth multiplicative
    return h >> (32 - LOGC_);                  // upper bits -> [0, C)
}

// bid -> (batch, chunk): batch = (bid&7) + 8*((bid>>3)&1)  => batch % 8 == bid % 8
__device__ __forceinline__ void swz(int bid, int& b, int& chunk) {
    b = (bid & 7) + (((bid >> 3) & 1) << 3);
    chunk = bid >> 4;
}

__global__ void k_build(const float* __restrict__ coords, ull* __restrict__ tab,
                        int* __restrict__ pslot) {
    int b, chunk;
    swz(blockIdx.x, b, chunk);                       // grid == B_*N_/256, 16 | grid
    int p = chunk * 256 + threadIdx.x;               // point within batch
    int i = (b << LOGN_) + p;
    const float* c = coords + (size_t)i * 3;
    // Must match jnp.floor(c / 0.2f) bit-exactly: IEEE fp32 division, no recip.
    int vx = (int)floorf(c[0] / 0.2f);
    int vy = (int)floorf(c[1] / 0.2f);
    int vz = (int)floorf(c[2] / 0.2f);
    int id = vx * 10000 + vy * 100 + vz;
    unsigned u = (unsigned)id ^ 0x80000000u;

    ull* t = tab + (size_t)b * C_;
    unsigned s = hash_id(id);
    while (true) {
        ull cur = t[s];              // plain load: stale-safe (slot id is monotone 0->u)
        if (cur == 0ull) {
            ull prev = atomicCAS(&t[s], 0ull, ((ull)u << 32) | 1ull);
            if (prev == 0ull) break;               // inserted
            cur = prev;
        }
        if ((unsigned)(cur >> 32) == u) {          // same voxel: one atomic increment
            atomicAdd(&t[s], 1ull);
            break;
        }
        s = (s + 1) & CMASK_;                      // collision: linear probe
    }
    pslot[i] = (int)s;
}

// Compact occupied slots into per-batch key arrays (block-aggregated append:
// ONE global atomic per 1024-thread block).
__global__ void __launch_bounds__(1024)
k_compact(const ull* __restrict__ tab, ull* __restrict__ ckeys,
          unsigned* __restrict__ csize) {
    int b, chunk;
    swz(blockIdx.x, b, chunk);                       // grid == B_*C_/1024, 16 | grid
    int i = b * C_ + chunk * 1024 + threadIdx.x;
    ull e = tab[i];
    bool valid = (e != 0ull);
    // priority key: (count desc, id asc) -> larger key = higher priority
    ull key = ((ull)(unsigned)e << 32) | (ull)(~(unsigned)(e >> 32));

    unsigned long long mask = __ballot(valid);
    int lane = threadIdx.x & 63;
    int wave = threadIdx.x >> 6;                     // 0..15

    __shared__ unsigned woff[16];
    __shared__ unsigned blockbase;
    if (lane == 0) woff[wave] = (unsigned)__popcll(mask);
    __syncthreads();
    if (threadIdx.x == 0) {
        unsigned tot = 0;
        for (int w2 = 0; w2 < 16; ++w2) { unsigned c = woff[w2]; woff[w2] = tot; tot += c; }
        blockbase = (tot != 0u) ? atomicAdd(&csize[b], tot) : 0u;
    }
    __syncthreads();
    if (valid) {
        unsigned pos = blockbase + woff[wave]
                     + (unsigned)__popcll(mask & ((1ull << lane) - 1ull));
        ckeys[(size_t)b * C_ + pos] = key;
    }
}

__global__ void __launch_bounds__(1024)
k_select(const unsigned* __restrict__ csize, const ull* __restrict__ ckeys,
         ull* __restrict__ tab) {
    int b = blockIdx.x;                              // batch b -> XCD b%8 (matches build)
    int U = (int)csize[b];
    const ull* keys = ckeys + (size_t)b * C_;

    __shared__ unsigned hist[1024];
    __shared__ ull skeys[K_];
    __shared__ int s_sel;
    __shared__ ull s_prefix;
    __shared__ int s_rem;

    int t = threadIdx.x;
    ull thr = 0ull;

    if (U > K_) {
        // MSB-first radix select with 10-bit digits: exact 256th-largest key.
        // Keys < 2^50 (count<=2^18 occupies bits 32..49), so 5 passes. Keys unique.
        ull prefix = 0ull;
        int rem = K_;
        for (int sh = 40; sh >= 0; sh -= 10) {
            hist[t] = 0u;
            __syncthreads();
            ull hi = ~0ull << (sh + 10);             // bits above current digit
            for (int i = t; i < U; i += 1024) {
                ull k = keys[i];
                if ((k & hi) == prefix)
                    atomicAdd(&hist[(unsigned)(k >> sh) & 1023u], 1u);
            }
            __syncthreads();
            if (t == 0) {
                int cum = 0;
                for (int bin = 1023; bin >= 0; --bin) {
                    int cc = (int)hist[bin];
                    if (cum + cc >= rem) {
                        s_prefix = prefix | ((ull)bin << sh);
                        s_rem = rem - cum;
                        break;
                    }
                    cum += cc;
                }
            }
            __syncthreads();
            prefix = s_prefix;
            rem = s_rem;
        }
        thr = prefix;  // exactly 256 keys are >= thr (keys unique)
    }

    if (t == 0) s_sel = 0;
    __syncthreads();
    for (int i = t; i < U; i += 1024) {
        ull k = keys[i];
        if (U <= K_ || k >= thr) { int p = atomicAdd(&s_sel, 1); skeys[p] = k; }
    }
    __syncthreads();
    int S = s_sel;  // ==256 when U>K, else ==U

    // Rank-sort the <=256 survivors; rank = final label.
    // U>K: rank by full key desc (count desc, id asc).
    // U<=K: labels are dense rank by id asc == low-32 (~u) desc.
    if (t < S) {
        ull k = skeys[t];
        int rank = 0;
        if (U > K_) {
            for (int j = 0; j < S; ++j) rank += (skeys[j] > k);
        } else {
            unsigned kl = (unsigned)k;
            for (int j = 0; j < S; ++j) rank += ((unsigned)skeys[j] > kl);
        }
        unsigned u = ~((unsigned)k);
        int id = (int)(u ^ 0x80000000u);
        ull* tb = tab + (size_t)b * C_;
        unsigned s = hash_id(id);
        while ((unsigned)(tb[s] >> 32) != u) s = (s + 1) & CMASK_;
        // Winner: rewrite entry low32 = ~rank (>= 0xFFFFFF00). High bits (u) kept,
        // so concurrent probes in this block still match correctly.
        tb[s] = ((ull)u << 32) | (ull)(~(unsigned)rank);
    }
}

__global__ void k_label(const int* __restrict__ pslot, const ull* __restrict__ tab,
                        int* __restrict__ out) {
    int b, chunk;
    swz(blockIdx.x, b, chunk);                       // grid == B_*N_/256
    int p = chunk * 256 + threadIdx.x;
    int i = (b << LOGN_) + p;
    ull e = tab[(size_t)b * C_ + pslot[i]];
    unsigned low = (unsigned)e;
    out[i] = (low >= 0xFFF00000u) ? (int)(~low) : -1;
}

extern "C" void kernel_launch(void* const* d_in, const int* in_sizes, int n_in,
                              void* d_out, int out_size, void* d_ws, size_t ws_size,
                              hipStream_t stream) {
    const float* coords = (const float*)d_in[0];
    int* out = (int*)d_out;

    // Workspace layout (80 MB + meta):
    char* w = (char*)d_ws;
    size_t off = 0;
    ull* tab = (ull*)(w + off);                 off += (size_t)B_ * C_ * 8;   // 32 MB
    int* pslot = (int*)(w + off);               off += (size_t)B_ * N_ * 4;   // 16 MB
    ull* ckeys = (ull*)(w + off);               off += (size_t)B_ * C_ * 8;   // 32 MB
    unsigned* csize = (unsigned*)(w + off);     // [B_]

    int blocksBN = B_ * N_ / 256;               // 16384, divisible by 16
    int blocksBC = B_ * C_ / 1024;              // 4096, divisible by 16

    hipMemsetAsync(tab, 0, (size_t)B_ * C_ * 8, stream);
    hipMemsetAsync(csize, 0, B_ * sizeof(unsigned), stream);
    k_build<<<blocksBN, 256, 0, stream>>>(coords, tab, pslot);
    k_compact<<<blocksBC, 1024, 0, stream>>>(tab, ckeys, csize);
    k_select<<<B_, 1024, 0, stream>>>(csize, ckeys, tab);
    k_label<<<blocksBN, 256, 0, stream>>>(pslot, tab, out);
}

// Round 6
// 427.027 us; speedup vs baseline: 20.3576x; 1.6361x over previous
//
#include <hip/hip_runtime.h>
#include <stdint.h>

// SuperpointGenerator: per-batch voxel id -> count -> top-256 by (count desc, id asc)
// -> labels 0..255 (else -1); if U<=256, label = dense rank by ascending id.
//
// Hash table entry (64-bit): (u << 32) | low32, where u = id ^ 0x80000000 (never 0).
//   During build:  low32 = count (<= 2^18 = 0x40000).
//   After select:  winners' low32 = ~rank (>= 0xFFFFFF00). Decode: low >= 0xFFF00000.
//
// XCD-locality: blocks are remapped so every block touching batch b's data has
// blockIdx % 8 == b % 8 (MI300-series round-robin block->XCD dispatch) -> batch
// b's table/keys live in XCD b%8's L2; atomics stay XCD-local.
//
// Top-256 selection: grid-parallel MSB-first radix select (5 passes x 10-bit
// digits over the 50-bit key), one hist+pick kernel pair per pass.

namespace {
constexpr int B_ = 16;
constexpr int N_ = 262144;          // 2^18 points per batch
constexpr int LOGN_ = 18;
constexpr int K_ = 256;
constexpr int LOGC_ = 18;
constexpr int C_ = 1 << LOGC_;      // hash table slots per batch
constexpr unsigned CMASK_ = C_ - 1;
typedef unsigned long long ull;
}

__device__ __forceinline__ unsigned hash_id(int id) {
    unsigned h = (unsigned)id * 2654435761u;   // Knuth multiplicative
    return h >> (32 - LOGC_);                  // upper bits -> [0, C)
}

// bid -> (batch, chunk): batch = (bid&7) + 8*((bid>>3)&1)  => batch % 8 == bid % 8
__device__ __forceinline__ void swz(int bid, int& b, int& chunk) {
    b = (bid & 7) + (((bid >> 3) & 1) << 3);
    chunk = bid >> 4;
}

__global__ void __launch_bounds__(1024)
k_init0(ull* __restrict__ pfx, unsigned* __restrict__ ghist,
        unsigned* __restrict__ csize, unsigned* __restrict__ gwc,
        unsigned* __restrict__ remg) {
    int b = blockIdx.x, t = threadIdx.x;       // grid == 16 x 1024
    ghist[b * 1024 + t] = 0u;
    if (t == 0) { csize[b] = 0u; gwc[b] = 0u; pfx[b] = 0ull; remg[b] = (unsigned)K_; }
}

__global__ void k_build(const float* __restrict__ coords, ull* __restrict__ tab,
                        int* __restrict__ pslot) {
    int b, chunk;
    swz(blockIdx.x, b, chunk);                       // grid == B_*N_/256
    int p = chunk * 256 + threadIdx.x;
    int i = (b << LOGN_) + p;
    const float* c = coords + (size_t)i * 3;
    // Must match jnp.floor(c / 0.2f) bit-exactly: IEEE fp32 division, no recip.
    int vx = (int)floorf(c[0] / 0.2f);
    int vy = (int)floorf(c[1] / 0.2f);
    int vz = (int)floorf(c[2] / 0.2f);
    int id = vx * 10000 + vy * 100 + vz;
    unsigned u = (unsigned)id ^ 0x80000000u;

    ull* t = tab + (size_t)b * C_;
    unsigned s = hash_id(id);
    while (true) {
        ull cur = t[s];              // plain load: stale-safe (slot id is monotone 0->u)
        if (cur == 0ull) {
            ull prev = atomicCAS(&t[s], 0ull, ((ull)u << 32) | 1ull);
            if (prev == 0ull) break;               // inserted
            cur = prev;
        }
        if ((unsigned)(cur >> 32) == u) {          // same voxel: one atomic increment
            atomicAdd(&t[s], 1ull);
            break;
        }
        s = (s + 1) & CMASK_;                      // collision: linear probe
    }
    pslot[i] = (int)s;
}

// Compact occupied slots into per-batch key arrays (block-aggregated append).
__global__ void __launch_bounds__(1024)
k_compact(const ull* __restrict__ tab, ull* __restrict__ ckeys,
          unsigned* __restrict__ csize) {
    int b, chunk;
    swz(blockIdx.x, b, chunk);                       // grid == B_*C_/1024
    int i = b * C_ + chunk * 1024 + threadIdx.x;
    ull e = tab[i];
    bool valid = (e != 0ull);
    // priority key: (count desc, id asc) -> larger key = higher priority
    ull key = ((ull)(unsigned)e << 32) | (ull)(~(unsigned)(e >> 32));

    unsigned long long mask = __ballot(valid);
    int lane = threadIdx.x & 63;
    int wave = threadIdx.x >> 6;                     // 0..15

    __shared__ unsigned woff[16];
    __shared__ unsigned blockbase;
    if (lane == 0) woff[wave] = (unsigned)__popcll(mask);
    __syncthreads();
    if (threadIdx.x == 0) {
        unsigned tot = 0;
        for (int w2 = 0; w2 < 16; ++w2) { unsigned c = woff[w2]; woff[w2] = tot; tot += c; }
        blockbase = (tot != 0u) ? atomicAdd(&csize[b], tot) : 0u;
    }
    __syncthreads();
    if (valid) {
        unsigned pos = blockbase + woff[wave]
                     + (unsigned)__popcll(mask & ((1ull << lane) - 1ull));
        ckeys[(size_t)b * C_ + pos] = key;
    }
}

// One radix pass histogram: keys matching current prefix contribute their 10-bit digit.
__global__ void __launch_bounds__(256)
k_hist(const unsigned* __restrict__ csize, const ull* __restrict__ ckeys,
       const ull* __restrict__ pfx, unsigned* __restrict__ ghist, int sh) {
    int b, chunk;
    swz(blockIdx.x, b, chunk);                       // grid == 128 -> chunk 0..7
    int U = (int)csize[b];
    if (U <= K_) return;
    ull prefix = pfx[b];
    ull hi = ~0ull << (sh + 10);                     // bits above current digit
    __shared__ unsigned lh[1024];
    for (int d = threadIdx.x; d < 1024; d += 256) lh[d] = 0u;
    __syncthreads();
    const ull* keys = ckeys + (size_t)b * C_;
    for (int i = chunk * 256 + threadIdx.x; i < U; i += 2048) {
        ull k = keys[i];
        if ((k & hi) == prefix)
            atomicAdd(&lh[(unsigned)(k >> sh) & 1023u], 1u);
    }
    __syncthreads();
    for (int d = threadIdx.x; d < 1024; d += 256) {
        unsigned c = lh[d];
        if (c) atomicAdd(&ghist[b * 1024 + d], c);
    }
}

// Pick the digit bin containing the rem-th largest; update prefix/rem; re-zero ghist.
__global__ void __launch_bounds__(1024)
k_pick(const unsigned* __restrict__ csize, unsigned* __restrict__ ghist,
       ull* __restrict__ pfx, unsigned* __restrict__ remg, int sh) {
    int b = blockIdx.x, t = threadIdx.x;             // grid == 16 x 1024
    unsigned cc = ghist[b * 1024 + t];
    ghist[b * 1024 + t] = 0u;                        // ready for next pass
    int U = (int)csize[b];
    if (U <= K_) return;
    __shared__ unsigned s[1024];
    s[t] = cc;
    __syncthreads();
    for (int off = 1; off < 1024; off <<= 1) {       // inclusive suffix sum
        unsigned v = (t + off < 1024) ? s[t + off] : 0u;
        __syncthreads();
        s[t] += v;
        __syncthreads();
    }
    unsigned rem = remg[b];
    unsigned Sincl = s[t];
    unsigned Sexcl = Sincl - cc;                     // sum of bins strictly above t
    if (Sexcl < rem && rem <= Sincl) {               // unique t (requires cc > 0)
        pfx[b] |= ((ull)t) << sh;
        remg[b] = rem - Sexcl;
    }
}

// Collect winners (keys >= threshold; all keys when U<=K) via block-aggregated append.
__global__ void __launch_bounds__(256)
k_collect(const unsigned* __restrict__ csize, const ull* __restrict__ ckeys,
          const ull* __restrict__ pfx, ull* __restrict__ gwin,
          unsigned* __restrict__ gwc) {
    int b, chunk;
    swz(blockIdx.x, b, chunk);                       // grid == 128
    int U = (int)csize[b];
    ull thr = pfx[b];                                // 0 when U<=K -> all pass
    const ull* keys = ckeys + (size_t)b * C_;
    __shared__ unsigned woff[4];
    __shared__ unsigned bbase;
    for (int i0 = chunk * 256; i0 < U; i0 += 2048) {
        int i = i0 + threadIdx.x;
        ull k = 0ull;
        bool valid = false;
        if (i < U) { k = keys[i]; valid = (k >= thr); }
        unsigned long long mask = __ballot(valid);
        int lane = threadIdx.x & 63, wave = threadIdx.x >> 6;
        if (lane == 0) woff[wave] = (unsigned)__popcll(mask);
        __syncthreads();
        if (threadIdx.x == 0) {
            unsigned tot = 0;
            for (int w2 = 0; w2 < 4; ++w2) { unsigned c = woff[w2]; woff[w2] = tot; tot += c; }
            bbase = (tot != 0u) ? atomicAdd(&gwc[b], tot) : 0u;
        }
        __syncthreads();
        if (valid) {
            unsigned pos = bbase + woff[wave]
                         + (unsigned)__popcll(mask & ((1ull << lane) - 1ull));
            gwin[b * K_ + pos] = k;
        }
        __syncthreads();                             // woff/bbase reused next iter
    }
}

// Rank-sort the <=256 winners; write labels into the hash table.
__global__ void __launch_bounds__(256)
k_rank(const unsigned* __restrict__ csize, const unsigned* __restrict__ gwc,
       const ull* __restrict__ gwin, ull* __restrict__ tab) {
    int b = blockIdx.x;                              // batch b -> XCD b%8
    int U = (int)csize[b];
    int S = (int)gwc[b];                             // ==256 when U>K, else ==U
    __shared__ ull sk[K_];
    int t = threadIdx.x;
    if (t < S) sk[t] = gwin[b * K_ + t];
    __syncthreads();
    if (t < S) {
        // U>K: rank by full key desc (count desc, id asc).
        // U<=K: dense rank by id asc == low-32 (~u) desc.
        ull k = sk[t];
        int rank = 0;
        if (U > K_) {
            for (int j = 0; j < S; ++j) rank += (sk[j] > k);
        } else {
            unsigned kl = (unsigned)k;
            for (int j = 0; j < S; ++j) rank += ((unsigned)sk[j] > kl);
        }
        unsigned u = ~((unsigned)k);
        int id = (int)(u ^ 0x80000000u);
        ull* tb = tab + (size_t)b * C_;
        unsigned s = hash_id(id);
        while ((unsigned)(tb[s] >> 32) != u) s = (s + 1) & CMASK_;
        tb[s] = ((ull)u << 32) | (ull)(~(unsigned)rank);
    }
}

__global__ void k_label(const int* __restrict__ pslot, const ull* __restrict__ tab,
                        int* __restrict__ out) {
    int b, chunk;
    swz(blockIdx.x, b, chunk);                       // grid == B_*N_/256
    int p = chunk * 256 + threadIdx.x;
    int i = (b << LOGN_) + p;
    ull e = tab[(size_t)b * C_ + pslot[i]];
    unsigned low = (unsigned)e;
    out[i] = (low >= 0xFFF00000u) ? (int)(~low) : -1;
}

extern "C" void kernel_launch(void* const* d_in, const int* in_sizes, int n_in,
                              void* d_out, int out_size, void* d_ws, size_t ws_size,
                              hipStream_t stream) {
    const float* coords = (const float*)d_in[0];
    int* out = (int*)d_out;

    // Workspace layout (~80 MB + 100 KB):
    char* w = (char*)d_ws;
    size_t off = 0;
    ull* tab = (ull*)(w + off);                 off += (size_t)B_ * C_ * 8;   // 32 MB
    int* pslot = (int*)(w + off);               off += (size_t)B_ * N_ * 4;   // 16 MB
    ull* ckeys = (ull*)(w + off);               off += (size_t)B_ * C_ * 8;   // 32 MB
    ull* pfx = (ull*)(w + off);                 off += B_ * 8;
    ull* gwin = (ull*)(w + off);                off += (size_t)B_ * K_ * 8;   // 32 KB
    unsigned* ghist = (unsigned*)(w + off);     off += (size_t)B_ * 1024 * 4; // 64 KB
    unsigned* csize = (unsigned*)(w + off);     off += B_ * 4;
    unsigned* gwc = (unsigned*)(w + off);       off += B_ * 4;
    unsigned* remg = (unsigned*)(w + off);      off += B_ * 4;

    int blocksBN = B_ * N_ / 256;               // 16384, divisible by 16
    int blocksBC = B_ * C_ / 1024;              // 4096, divisible by 16

    hipMemsetAsync(tab, 0, (size_t)B_ * C_ * 8, stream);
    k_init0<<<B_, 1024, 0, stream>>>(pfx, ghist, csize, gwc, remg);
    k_build<<<blocksBN, 256, 0, stream>>>(coords, tab, pslot);
    k_compact<<<blocksBC, 1024, 0, stream>>>(tab, ckeys, csize);
    for (int sh = 40; sh >= 0; sh -= 10) {
        k_hist<<<128, 256, 0, stream>>>(csize, ckeys, pfx, ghist, sh);
        k_pick<<<B_, 1024, 0, stream>>>(csize, ghist, pfx, remg, sh);
    }
    k_collect<<<128, 256, 0, stream>>>(csize, ckeys, pfx, gwin, gwc);
    k_rank<<<B_, 256, 0, stream>>>(csize, gwc, gwin, tab);
    k_label<<<blocksBN, 256, 0, stream>>>(pslot, tab, out);
}